// Round 1
// baseline (273.529 us; speedup 1.0000x reference)
//
#include <hip/hip_runtime.h>

using bfrag = __attribute__((ext_vector_type(8))) __bf16;
using f32x4 = __attribute__((ext_vector_type(4))) float;

__device__ __forceinline__ ushort f2bf(float f) {
    union { float f; unsigned u; } c; c.f = f;
    return (ushort)((c.u + 0x7fffu + ((c.u >> 16) & 1u)) >> 16);
}

__device__ __forceinline__ void gld_lds16(const ushort* g, ushort* l) {
    __builtin_amdgcn_global_load_lds(
        (const __attribute__((address_space(1))) void*)g,
        (__attribute__((address_space(3))) void*)l, 16, 0, 0);
}

// ---------------- conversion kernels ----------------

__global__ void cvt_bf16(const float* __restrict__ src, ushort* __restrict__ dst, int n4) {
    int i = blockIdx.x * blockDim.x + threadIdx.x;
    if (i < n4) {
        float4 f = ((const float4*)src)[i];
        ushort4 o = make_ushort4(f2bf(f.x), f2bf(f.y), f2bf(f.z), f2bf(f.w));
        ((ushort4*)dst)[i] = o;
    }
}

// fp32 [1024][1024] -> bf16 transposed [1024][1024]
__global__ void cvt_T(const float* __restrict__ src, ushort* __restrict__ dst) {
    __shared__ float t[32][33];
    const int tx = threadIdx.x, ty = threadIdx.y;
    const int c0 = blockIdx.x * 32, r0 = blockIdx.y * 32;
    for (int i = ty; i < 32; i += 8) t[i][tx] = src[(size_t)(r0 + i) * 1024 + c0 + tx];
    __syncthreads();
    for (int i = ty; i < 32; i += 8) dst[(size_t)(c0 + i) * 1024 + r0 + tx] = f2bf(t[tx][i]);
}

// ---------------- GEMM: C[4096,1024] = A[4096,1024] @ Bt[1024,1024]^T, bias, scale ----------------
// 128x128 tile, BK=32, 256 threads = 4 waves (2x2), each wave 64x64 (4x4 16x16x32 frags)

template<bool BF16OUT>
__global__ __launch_bounds__(256) void gemm_bt(
    const ushort* __restrict__ A, const ushort* __restrict__ Bt,
    const float* __restrict__ bias, void* __restrict__ Cout,
    ushort* __restrict__ vpt, float scale)
{
    __shared__ ushort As[128 * 32];
    __shared__ ushort Bs[128 * 32];
    const int tid = threadIdx.x;
    const int lane = tid & 63, w = tid >> 6;
    const int l15 = lane & 15, lg = lane >> 4;
    const int bM = blockIdx.y, bN = blockIdx.x;
    const int wr = w >> 1, wc = w & 1;

    const ushort* Ag = A + (size_t)bM * 128 * 1024;
    const ushort* Bg = Bt + (size_t)bN * 128 * 1024;
    const int r0 = w * 32 + (lane >> 2);   // staging row for chunk i=0
    const int cc = (lane & 3) * 8;         // staging col (elements)

    f32x4 acc[4][4];
#pragma unroll
    for (int m = 0; m < 4; ++m)
#pragma unroll
        for (int n = 0; n < 4; ++n) acc[m][n] = (f32x4){0.f, 0.f, 0.f, 0.f};

    for (int kt = 0; kt < 32; ++kt) {
        const int kk = kt * 32;
#pragma unroll
        for (int i = 0; i < 2; ++i) {
            const int row = r0 + i * 16;
            const int c = w * 2 + i;      // chunk 0..7, wave-uniform
            gld_lds16(Ag + (size_t)row * 1024 + kk + cc, &As[c * 512]);
            gld_lds16(Bg + (size_t)row * 1024 + kk + cc, &Bs[c * 512]);
        }
        __syncthreads();
        bfrag aF[4], bF[4];
#pragma unroll
        for (int m = 0; m < 4; ++m) aF[m] = *(const bfrag*)&As[(wr * 64 + m * 16 + l15) * 32 + lg * 8];
#pragma unroll
        for (int n = 0; n < 4; ++n) bF[n] = *(const bfrag*)&Bs[(wc * 64 + n * 16 + l15) * 32 + lg * 8];
#pragma unroll
        for (int m = 0; m < 4; ++m)
#pragma unroll
            for (int n = 0; n < 4; ++n)
                acc[m][n] = __builtin_amdgcn_mfma_f32_16x16x32_bf16(aF[m], bF[n], acc[m][n], 0, 0, 0);
        __syncthreads();
    }

#pragma unroll
    for (int m = 0; m < 4; ++m)
#pragma unroll
        for (int n = 0; n < 4; ++n) {
            const int gcol = bN * 128 + wc * 64 + n * 16 + l15;
            const float bv = bias[gcol];
#pragma unroll
            for (int j = 0; j < 4; ++j) {
                const int grow = bM * 128 + wr * 64 + m * 16 + lg * 4 + j;
                const float val = (acc[m][n][j] + bv) * scale;
                if constexpr (BF16OUT) {
                    ((ushort*)Cout)[(size_t)grow * 1024 + gcol] = f2bf(val);
                    if (vpt) {   // also scatter V^T per head: vpt[((b*16+h)*64+d)*2048 + s]
                        const int b_ = grow >> 11, s_ = grow & 2047;
                        const int h_ = gcol >> 6, d_ = gcol & 63;
                        vpt[(size_t)((b_ * 16 + h_) * 64 + d_) * 2048 + s_] = f2bf(val);
                    }
                } else {
                    ((float*)Cout)[(size_t)grow * 1024 + gcol] = val;
                }
            }
        }
}

// ---------------- flash attention ----------------
// QP: bf16 [4096][1024], pre-scaled by 0.125*log2e. VP: bf16 [4096][1024] (keys AND values).
// VPT: bf16 [32][64][2048] per-head V^T. AO: bf16 [4096][1024].
// grid (16 qtiles, 32 bh), 256 threads = 4 waves, wave w owns 32 q-rows.

__global__ __launch_bounds__(256, 2) void attn_kernel(
    const ushort* __restrict__ QP, const ushort* __restrict__ VP,
    const ushort* __restrict__ VPT, ushort* __restrict__ AO)
{
    __shared__ ushort Plds[4 * 2048];   // per-wave 32x64 bf16, XOR-swizzled
    const int tid = threadIdx.x;
    const int w = tid >> 6, lane = tid & 63;
    const int l15 = lane & 15, lg = lane >> 4;
    const int qt = blockIdx.x, bh = blockIdx.y;
    const int b = bh >> 4, h = bh & 15;
    const int qrow0 = qt * 128 + w * 32;

    const ushort* Qb = QP + ((size_t)(b * 2048 + qrow0)) * 1024 + h * 64;
    const ushort* Kb = VP + ((size_t)(b * 2048)) * 1024 + h * 64;
    const ushort* Vt = VPT + (size_t)bh * 64 * 2048;
    ushort* Pw = &Plds[w * 2048];

    // Q fragments hoisted to registers (A-operand: rows = q, k = d)
    bfrag qF[2][2];
#pragma unroll
    for (int m = 0; m < 2; ++m)
#pragma unroll
        for (int ks = 0; ks < 2; ++ks)
            qF[m][ks] = *(const bfrag*)(Qb + (size_t)(m * 16 + l15) * 1024 + ks * 32 + lg * 8);

    f32x4 O[2][4];
    float mrun[2][4], lrun[2][4];
#pragma unroll
    for (int m = 0; m < 2; ++m)
#pragma unroll
        for (int n = 0; n < 4; ++n) O[m][n] = (f32x4){0.f, 0.f, 0.f, 0.f};
#pragma unroll
    for (int m = 0; m < 2; ++m)
#pragma unroll
        for (int j = 0; j < 4; ++j) { mrun[m][j] = -1e30f; lrun[m][j] = 0.f; }

    for (int kt = 0; kt < 32; ++kt) {
        const ushort* Kt = Kb + (size_t)(kt * 64) * 1024;
        bfrag kF[4][2];   // B-operand: cols = s_k, k = d (16B contiguous in d)
#pragma unroll
        for (int nf = 0; nf < 4; ++nf)
#pragma unroll
            for (int ks = 0; ks < 2; ++ks)
                kF[nf][ks] = *(const bfrag*)(Kt + (size_t)(nf * 16 + l15) * 1024 + ks * 32 + lg * 8);

        const f32x4 z4 = {0.f, 0.f, 0.f, 0.f};
        f32x4 S[2][4];
#pragma unroll
        for (int m = 0; m < 2; ++m)
#pragma unroll
            for (int nf = 0; nf < 4; ++nf)
                S[m][nf] = __builtin_amdgcn_mfma_f32_16x16x32_bf16(qF[m][0], kF[nf][0], z4, 0, 0, 0);
#pragma unroll
        for (int m = 0; m < 2; ++m)
#pragma unroll
            for (int nf = 0; nf < 4; ++nf)
                S[m][nf] = __builtin_amdgcn_mfma_f32_16x16x32_bf16(qF[m][1], kF[nf][1], S[m][nf], 0, 0, 0);

        // online softmax: S row = lg*4+j (+16*m), col = l15 (+16*nf). exp2 domain (Q pre-scaled).
        float resc[2][4];
#pragma unroll
        for (int m = 0; m < 2; ++m)
#pragma unroll
            for (int j = 0; j < 4; ++j) {
                float vmax = fmaxf(fmaxf(S[m][0][j], S[m][1][j]), fmaxf(S[m][2][j], S[m][3][j]));
                vmax = fmaxf(vmax, __shfl_xor(vmax, 1));
                vmax = fmaxf(vmax, __shfl_xor(vmax, 2));
                vmax = fmaxf(vmax, __shfl_xor(vmax, 4));
                vmax = fmaxf(vmax, __shfl_xor(vmax, 8));
                const float mold = mrun[m][j];
                const float mnew = fmaxf(mold, vmax);
                const float r = __builtin_amdgcn_exp2f(mold - mnew);
                float s = 0.f;
#pragma unroll
                for (int nf = 0; nf < 4; ++nf) {
                    const float p = __builtin_amdgcn_exp2f(S[m][nf][j] - mnew);
                    S[m][nf][j] = p;
                    s += p;
                }
                s += __shfl_xor(s, 1);
                s += __shfl_xor(s, 2);
                s += __shfl_xor(s, 4);
                s += __shfl_xor(s, 8);
                mrun[m][j] = mnew;
                lrun[m][j] = lrun[m][j] * r + s;
                resc[m][j] = r;
            }
#pragma unroll
        for (int m = 0; m < 2; ++m)
#pragma unroll
            for (int nf = 0; nf < 4; ++nf)
#pragma unroll
                for (int j = 0; j < 4; ++j) O[m][nf][j] *= resc[m][j];

        // P -> LDS (bf16, XOR-swizzled rows so b128 reads are conflict-free)
#pragma unroll
        for (int m = 0; m < 2; ++m)
#pragma unroll
            for (int nf = 0; nf < 4; ++nf)
#pragma unroll
                for (int j = 0; j < 4; ++j) {
                    const int qq = m * 16 + lg * 4 + j;
                    const int sc = nf * 16 + l15;
                    const int boff = qq * 128 + ((sc * 2) ^ ((qq & 7) << 4));
                    Pw[boff >> 1] = f2bf(S[m][nf][j]);
                }
        asm volatile("s_waitcnt lgkmcnt(0)" ::: "memory");

        // PV: A = P (rows q, k = s), B = V^T (cols d, k = s)
        bfrag pF[2][2];
#pragma unroll
        for (int m = 0; m < 2; ++m)
#pragma unroll
            for (int ks = 0; ks < 2; ++ks) {
                const int qq = m * 16 + l15;
                const int boff = qq * 128 + (((ks * 64) + lg * 16) ^ ((qq & 7) << 4));
                pF[m][ks] = *(const bfrag*)&Pw[boff >> 1];
            }
#pragma unroll
        for (int nf = 0; nf < 4; ++nf)
#pragma unroll
            for (int ks = 0; ks < 2; ++ks) {
                const bfrag vF = *(const bfrag*)(Vt + (size_t)(nf * 16 + l15) * 2048 + kt * 64 + ks * 32 + lg * 8);
#pragma unroll
                for (int m = 0; m < 2; ++m)
                    O[m][nf] = __builtin_amdgcn_mfma_f32_16x16x32_bf16(pF[m][ks], vF, O[m][nf], 0, 0, 0);
            }
    }

    // epilogue: O / l, write bf16
#pragma unroll
    for (int m = 0; m < 2; ++m)
#pragma unroll
        for (int j = 0; j < 4; ++j) {
            const float inv = 1.f / lrun[m][j];
#pragma unroll
            for (int nf = 0; nf < 4; ++nf) {
                const int qq = m * 16 + lg * 4 + j;
                const size_t grow = (size_t)(b * 2048 + qrow0 + qq);
                const int gcol = h * 64 + nf * 16 + l15;
                AO[grow * 1024 + gcol] = f2bf(O[m][nf][j] * inv);
            }
        }
}

// ---------------- launcher ----------------

extern "C" void kernel_launch(void* const* d_in, const int* in_sizes, int n_in,
                              void* d_out, int out_size, void* d_ws, size_t ws_size,
                              hipStream_t stream) {
    (void)in_sizes; (void)n_in; (void)out_size; (void)ws_size;
    const float* q  = (const float*)d_in[0];
    const float* v  = (const float*)d_in[2];
    const float* Wq = (const float*)d_in[3];
    const float* bq = (const float*)d_in[4];
    const float* Wv = (const float*)d_in[7];
    const float* bv = (const float*)d_in[8];
    const float* Wo = (const float*)d_in[9];
    const float* bo = (const float*)d_in[10];
    float* out = (float*)d_out;
    char* ws = (char*)d_ws;
    const size_t MB = 1ull << 20;
    ushort* qbf = (ushort*)(ws + 0);         // 8MB (reused as AO)
    ushort* vbf = (ushort*)(ws + 8 * MB);    // 8MB
    ushort* WqT = (ushort*)(ws + 16 * MB);   // 2MB
    ushort* WvT = (ushort*)(ws + 18 * MB);   // 2MB
    ushort* WoT = (ushort*)(ws + 20 * MB);   // 2MB
    ushort* QPb = (ushort*)(ws + 22 * MB);   // 8MB
    ushort* VPb = (ushort*)(ws + 30 * MB);   // 8MB
    ushort* VPT = (ushort*)(ws + 38 * MB);   // 8MB
    ushort* AO  = qbf;                        // alias: qbf dead after q-proj GEMM

    cvt_bf16<<<4096, 256, 0, stream>>>(q, qbf, 1048576);
    cvt_bf16<<<4096, 256, 0, stream>>>(v, vbf, 1048576);
    dim3 tb(32, 8);
    cvt_T<<<dim3(32, 32), tb, 0, stream>>>(Wq, WqT);
    cvt_T<<<dim3(32, 32), tb, 0, stream>>>(Wv, WvT);
    cvt_T<<<dim3(32, 32), tb, 0, stream>>>(Wo, WoT);

    // q-proj pre-scaled by 0.125*log2(e) so attention runs in exp2 domain
    const float qscale = 0.125f * 1.44269504088896340736f;
    gemm_bt<true><<<dim3(8, 32), 256, 0, stream>>>(qbf, WqT, bq, QPb, nullptr, qscale);
    gemm_bt<true><<<dim3(8, 32), 256, 0, stream>>>(vbf, WvT, bv, VPb, VPT, 1.0f);
    attn_kernel<<<dim3(16, 32), 256, 0, stream>>>(QPb, VPb, VPT, AO);
    gemm_bt<false><<<dim3(8, 32), 256, 0, stream>>>(AO, WoT, bo, out, nullptr, 1.0f);
}

// Round 3
// 220.661 us; speedup vs baseline: 1.2396x; 1.2396x over previous
//
#include <hip/hip_runtime.h>
#include <hip/hip_bf16.h>

using bfrag  = __attribute__((ext_vector_type(8))) __bf16;
using f32x4  = __attribute__((ext_vector_type(4))) float;
using f32x16 = __attribute__((ext_vector_type(16))) float;
using v4u    = __attribute__((ext_vector_type(4))) unsigned int;
using v2u    = __attribute__((ext_vector_type(2))) unsigned int;

__device__ __forceinline__ ushort f2bf(float f) {
    union { float f; unsigned u; } c; c.f = f;
    return (ushort)((c.u + 0x7fffu + ((c.u >> 16) & 1u)) >> 16);
}

__device__ __forceinline__ unsigned pack_bf16x2(float lo, float hi) {
    union { __hip_bfloat162 h; unsigned u; } c;
    c.h = __float22bfloat162_rn(make_float2(lo, hi));   // lo -> low ushort, hi -> high
    return c.u;
}

__device__ __forceinline__ void gld_lds16(const ushort* g, ushort* l) {
    __builtin_amdgcn_global_load_lds(
        (const __attribute__((address_space(1))) void*)g,
        (__attribute__((address_space(3))) void*)l, 16, 0, 0);
}

__device__ __forceinline__ f32x16 mfma32(bfrag a, bfrag b, f32x16 c) {
    return __builtin_amdgcn_mfma_f32_32x32x16_bf16(a, b, c, 0, 0, 0);
}

// ---------------- conversion kernels ----------------

__global__ void cvt_bf16(const float* __restrict__ src, ushort* __restrict__ dst, int n4) {
    int i = blockIdx.x * blockDim.x + threadIdx.x;
    if (i < n4) {
        float4 f = ((const float4*)src)[i];
        ushort4 o = make_ushort4(f2bf(f.x), f2bf(f.y), f2bf(f.z), f2bf(f.w));
        ((ushort4*)dst)[i] = o;
    }
}

// fp32 [1024][1024] -> bf16 transposed [1024][1024]
__global__ void cvt_T(const float* __restrict__ src, ushort* __restrict__ dst) {
    __shared__ float t[32][33];
    const int tx = threadIdx.x, ty = threadIdx.y;
    const int c0 = blockIdx.x * 32, r0 = blockIdx.y * 32;
    for (int i = ty; i < 32; i += 8) t[i][tx] = src[(size_t)(r0 + i) * 1024 + c0 + tx];
    __syncthreads();
    for (int i = ty; i < 32; i += 8) dst[(size_t)(c0 + i) * 1024 + r0 + tx] = f2bf(t[tx][i]);
}

// ---------------- GEMM: C[4096,1024] = A[4096,1024] @ Bt[1024,1024]^T, bias, scale ----------------

template<bool BF16OUT>
__global__ __launch_bounds__(256) void gemm_bt(
    const ushort* __restrict__ A, const ushort* __restrict__ Bt,
    const float* __restrict__ bias, void* __restrict__ Cout,
    ushort* __restrict__ vpt, float scale)
{
    __shared__ ushort As[128 * 32];
    __shared__ ushort Bs[128 * 32];
    const int tid = threadIdx.x;
    const int lane = tid & 63, w = tid >> 6;
    const int l15 = lane & 15, lg = lane >> 4;
    const int bM = blockIdx.y, bN = blockIdx.x;
    const int wr = w >> 1, wc = w & 1;

    const ushort* Ag = A + (size_t)bM * 128 * 1024;
    const ushort* Bg = Bt + (size_t)bN * 128 * 1024;
    const int r0 = w * 32 + (lane >> 2);
    const int cc = (lane & 3) * 8;

    f32x4 acc[4][4];
#pragma unroll
    for (int m = 0; m < 4; ++m)
#pragma unroll
        for (int n = 0; n < 4; ++n) acc[m][n] = (f32x4){0.f, 0.f, 0.f, 0.f};

    for (int kt = 0; kt < 32; ++kt) {
        const int kk = kt * 32;
#pragma unroll
        for (int i = 0; i < 2; ++i) {
            const int row = r0 + i * 16;
            const int c = w * 2 + i;
            gld_lds16(Ag + (size_t)row * 1024 + kk + cc, &As[c * 512]);
            gld_lds16(Bg + (size_t)row * 1024 + kk + cc, &Bs[c * 512]);
        }
        __syncthreads();
        bfrag aF[4], bF[4];
#pragma unroll
        for (int m = 0; m < 4; ++m) aF[m] = *(const bfrag*)&As[(wr * 64 + m * 16 + l15) * 32 + lg * 8];
#pragma unroll
        for (int n = 0; n < 4; ++n) bF[n] = *(const bfrag*)&Bs[(wc * 64 + n * 16 + l15) * 32 + lg * 8];
#pragma unroll
        for (int m = 0; m < 4; ++m)
#pragma unroll
            for (int n = 0; n < 4; ++n)
                acc[m][n] = __builtin_amdgcn_mfma_f32_16x16x32_bf16(aF[m], bF[n], acc[m][n], 0, 0, 0);
        __syncthreads();
    }

#pragma unroll
    for (int m = 0; m < 4; ++m)
#pragma unroll
        for (int n = 0; n < 4; ++n) {
            const int gcol = bN * 128 + wc * 64 + n * 16 + l15;
            const float bv = bias[gcol];
#pragma unroll
            for (int j = 0; j < 4; ++j) {
                const int grow = bM * 128 + wr * 64 + m * 16 + lg * 4 + j;
                const float val = (acc[m][n][j] + bv) * scale;
                if constexpr (BF16OUT) {
                    ((ushort*)Cout)[(size_t)grow * 1024 + gcol] = f2bf(val);
                    if (vpt) {
                        // V^T per head, s-index bit2<->bit3 swapped within each 16-block
                        // so attention's PV can consume P fragments with NO cross-lane repack.
                        const int b_ = grow >> 11, s_ = grow & 2047;
                        const int h_ = gcol >> 6, d_ = gcol & 63;
                        const int s2 = (s_ & ~15) | (s_ & 3) | ((s_ >> 1) & 4) | ((s_ << 1) & 8);
                        vpt[(size_t)((b_ * 16 + h_) * 64 + d_) * 2048 + s2] = f2bf(val);
                    }
                } else {
                    ((float*)Cout)[(size_t)grow * 1024 + gcol] = val;
                }
            }
        }
}

// ---------------- flash attention, swapped-operand 32x32 MFMA ----------------
// QP: bf16 [4096][1024] pre-scaled by 0.125*log2e. VP: bf16 [4096][1024] (keys AND values).
// VPT: bf16 [32][64][2048] per-head V^T with sigma(bit2<->bit3)-permuted s within 16-blocks.
// AO: bf16 [4096][1024].
// grid (16 qtiles, 32 bh), 256 thr = 4 waves; wave owns 32 q-rows; KVBLK=64.
// S^T = mfma(K, Q^T): lane holds col q=lane&31, rows kv=(r&3)+8*(r>>2)+4*hi.
// PV: B-operand k-slot s=hi*8+t fed with own p[8c+t] => effective kv = sigma(s);
//     VPT pre-permuted by sigma so the contraction lines up. No permlane needed.

__global__ __launch_bounds__(256, 2) void attn_kernel(
    const ushort* __restrict__ QP, const ushort* __restrict__ VP,
    const ushort* __restrict__ VPT, ushort* __restrict__ AO)
{
    const int tid = threadIdx.x;
    const int w = tid >> 6, lane = tid & 63;
    const int l31 = lane & 31, hi = lane >> 5;
    const int qt = blockIdx.x, bh = blockIdx.y;
    const int b = bh >> 4, h = bh & 15;
    const int qrow0 = qt * 128 + w * 32;

    const ushort* Qp = QP + ((size_t)(b * 2048 + qrow0 + l31)) * 1024 + h * 64 + hi * 8;
    const ushort* Kp = VP + ((size_t)(b * 2048 + l31)) * 1024 + h * 64 + hi * 8;
    const ushort* Vt = VPT + (size_t)bh * 64 * 2048 + (size_t)l31 * 2048 + hi * 8;

    // Q fragments (B-operand): lane holds Q[q=l31][ds*16 + 8*hi + t]
    bfrag qB[4];
#pragma unroll
    for (int ds = 0; ds < 4; ++ds) qB[ds] = *(const bfrag*)(Qp + ds * 16);

    f32x16 O0, O1;
#pragma unroll
    for (int r = 0; r < 16; ++r) { O0[r] = 0.f; O1[r] = 0.f; }
    float mrun = -1e30f, lrun = 0.f;

    for (int kt = 0; kt < 32; ++kt) {
        const ushort* Kt = Kp + (size_t)(kt * 64) * 1024;
        bfrag kA0[4], kA1[4];   // A-operand: lane holds K[kv=l31(+32)][ds*16 + 8*hi + t]
#pragma unroll
        for (int ds = 0; ds < 4; ++ds) {
            kA0[ds] = *(const bfrag*)(Kt + ds * 16);
            kA1[ds] = *(const bfrag*)(Kt + 32 * 1024 + ds * 16);
        }
        f32x16 S0, S1;
#pragma unroll
        for (int r = 0; r < 16; ++r) { S0[r] = 0.f; S1[r] = 0.f; }
        __builtin_amdgcn_s_setprio(1);
#pragma unroll
        for (int ds = 0; ds < 4; ++ds) S0 = mfma32(kA0[ds], qB[ds], S0);
#pragma unroll
        for (int ds = 0; ds < 4; ++ds) S1 = mfma32(kA1[ds], qB[ds], S1);
        __builtin_amdgcn_s_setprio(0);

        // ---- online softmax, fully in-register (exp2 domain) ----
        float mx[8];
#pragma unroll
        for (int i = 0; i < 8; ++i)
            mx[i] = fmaxf(fmaxf(S0[i], S0[i + 8]), fmaxf(S1[i], S1[i + 8]));
        const float m4 = fmaxf(fmaxf(mx[0], mx[1]), fmaxf(mx[2], mx[3]));
        const float m5 = fmaxf(fmaxf(mx[4], mx[5]), fmaxf(mx[6], mx[7]));
        float pmax = fmaxf(m4, m5);
        pmax = fmaxf(pmax, __shfl_xor(pmax, 32));

        if (!__all(pmax - mrun <= 8.0f)) {   // defer-max (T13)
            const float mnew = fmaxf(mrun, pmax);
            const float rsc = __builtin_amdgcn_exp2f(mrun - mnew);
            mrun = mnew;
            lrun *= rsc;
#pragma unroll
            for (int r = 0; r < 16; ++r) { O0[r] *= rsc; O1[r] *= rsc; }
        }

        float p[32];
#pragma unroll
        for (int r = 0; r < 16; ++r) {
            p[r]      = __builtin_amdgcn_exp2f(S0[r] - mrun);
            p[16 + r] = __builtin_amdgcn_exp2f(S1[r] - mrun);
        }
        float s8[8];
#pragma unroll
        for (int i = 0; i < 8; ++i) s8[i] = (p[i] + p[i + 8]) + (p[i + 16] + p[i + 24]);
        float ssum = ((s8[0] + s8[1]) + (s8[2] + s8[3])) + ((s8[4] + s8[5]) + (s8[6] + s8[7]));
        ssum += __shfl_xor(ssum, 32);
        lrun += ssum;

        // ---- pack P -> bf16 B-fragments, exchange-free (kv permuted by sigma; VPT matches) ----
        bfrag pB[4];
#pragma unroll
        for (int c = 0; c < 4; ++c) {
            union { v4u u; bfrag f; } cv;
#pragma unroll
            for (int wd = 0; wd < 4; ++wd)
                cv.u[wd] = pack_bf16x2(p[8 * c + 2 * wd], p[8 * c + 2 * wd + 1]);
            pB[c] = cv.f;
        }

        // ---- PV (swapped): O^T += V^T-frag x P^T-frag ----
        const ushort* Vkt = Vt + kt * 64;
        __builtin_amdgcn_s_setprio(1);
#pragma unroll
        for (int c = 0; c < 4; ++c)
            O0 = mfma32(*(const bfrag*)(Vkt + c * 16), pB[c], O0);
#pragma unroll
        for (int c = 0; c < 4; ++c)
            O1 = mfma32(*(const bfrag*)(Vkt + 65536 + c * 16), pB[c], O1);
        __builtin_amdgcn_s_setprio(0);
    }

    // ---- epilogue: O^T / l -> AO[q][h*64+d], 8B packed stores ----
    const float inv = 1.f / lrun;
    ushort* Ao = AO + (size_t)(b * 2048 + qrow0 + l31) * 1024 + h * 64 + hi * 4;
#pragma unroll
    for (int t = 0; t < 2; ++t) {
#pragma unroll
        for (int g = 0; g < 4; ++g) {
            const float e0 = (t ? O1[4 * g + 0] : O0[4 * g + 0]) * inv;
            const float e1 = (t ? O1[4 * g + 1] : O0[4 * g + 1]) * inv;
            const float e2 = (t ? O1[4 * g + 2] : O0[4 * g + 2]) * inv;
            const float e3 = (t ? O1[4 * g + 3] : O0[4 * g + 3]) * inv;
            v2u pk = (v2u){pack_bf16x2(e0, e1), pack_bf16x2(e2, e3)};
            *(v2u*)(Ao + t * 32 + g * 8) = pk;
        }
    }
}

// ---------------- launcher ----------------

extern "C" void kernel_launch(void* const* d_in, const int* in_sizes, int n_in,
                              void* d_out, int out_size, void* d_ws, size_t ws_size,
                              hipStream_t stream) {
    (void)in_sizes; (void)n_in; (void)out_size; (void)ws_size;
    const float* q  = (const float*)d_in[0];
    const float* v  = (const float*)d_in[2];
    const float* Wq = (const float*)d_in[3];
    const float* bq = (const float*)d_in[4];
    const float* Wv = (const float*)d_in[7];
    const float* bv = (const float*)d_in[8];
    const float* Wo = (const float*)d_in[9];
    const float* bo = (const float*)d_in[10];
    float* out = (float*)d_out;
    char* ws = (char*)d_ws;
    const size_t MB = 1ull << 20;
    ushort* qbf = (ushort*)(ws + 0);         // 8MB (reused as AO)
    ushort* vbf = (ushort*)(ws + 8 * MB);    // 8MB
    ushort* WqT = (ushort*)(ws + 16 * MB);   // 2MB
    ushort* WvT = (ushort*)(ws + 18 * MB);   // 2MB
    ushort* WoT = (ushort*)(ws + 20 * MB);   // 2MB
    ushort* QPb = (ushort*)(ws + 22 * MB);   // 8MB
    ushort* VPb = (ushort*)(ws + 30 * MB);   // 8MB
    ushort* VPT = (ushort*)(ws + 38 * MB);   // 8MB
    ushort* AO  = qbf;                        // alias: qbf dead after q-proj GEMM

    cvt_bf16<<<4096, 256, 0, stream>>>(q, qbf, 1048576);
    cvt_bf16<<<4096, 256, 0, stream>>>(v, vbf, 1048576);
    dim3 tb(32, 8);
    cvt_T<<<dim3(32, 32), tb, 0, stream>>>(Wq, WqT);
    cvt_T<<<dim3(32, 32), tb, 0, stream>>>(Wv, WvT);
    cvt_T<<<dim3(32, 32), tb, 0, stream>>>(Wo, WoT);

    const float qscale = 0.125f * 1.44269504088896340736f;
    gemm_bt<true><<<dim3(8, 32), 256, 0, stream>>>(qbf, WqT, bq, QPb, nullptr, qscale);
    gemm_bt<true><<<dim3(8, 32), 256, 0, stream>>>(vbf, WvT, bv, VPb, VPT, 1.0f);
    attn_kernel<<<dim3(16, 32), 256, 0, stream>>>(QPb, VPb, VPT, AO);
    gemm_bt<false><<<dim3(8, 32), 256, 0, stream>>>(AO, WoT, bo, out, nullptr, 1.0f);
}

// Round 4
// 207.760 us; speedup vs baseline: 1.3166x; 1.0621x over previous
//
#include <hip/hip_runtime.h>
#include <hip/hip_bf16.h>

using bfrag  = __attribute__((ext_vector_type(8))) __bf16;
using f32x4  = __attribute__((ext_vector_type(4))) float;
using f32x16 = __attribute__((ext_vector_type(16))) float;
using v4u    = __attribute__((ext_vector_type(4))) unsigned int;
using v2u    = __attribute__((ext_vector_type(2))) unsigned int;

__device__ __forceinline__ ushort f2bf(float f) {
    union { float f; unsigned u; } c; c.f = f;
    return (ushort)((c.u + 0x7fffu + ((c.u >> 16) & 1u)) >> 16);
}

__device__ __forceinline__ unsigned pack_bf16x2(float lo, float hi) {
    union { __hip_bfloat162 h; unsigned u; } c;
    c.h = __float22bfloat162_rn(make_float2(lo, hi));   // lo -> low ushort, hi -> high
    return c.u;
}

__device__ __forceinline__ void gld_lds16(const ushort* g, ushort* l) {
    __builtin_amdgcn_global_load_lds(
        (const __attribute__((address_space(1))) void*)g,
        (__attribute__((address_space(3))) void*)l, 16, 0, 0);
}

__device__ __forceinline__ f32x16 mfma32(bfrag a, bfrag b, f32x16 c) {
    return __builtin_amdgcn_mfma_f32_32x32x16_bf16(a, b, c, 0, 0, 0);
}

// ---------------- conversion kernels ----------------

__global__ void cvt_bf16(const float* __restrict__ src, ushort* __restrict__ dst, int n4) {
    int i = blockIdx.x * blockDim.x + threadIdx.x;
    if (i < n4) {
        float4 f = ((const float4*)src)[i];
        ushort4 o = make_ushort4(f2bf(f.x), f2bf(f.y), f2bf(f.z), f2bf(f.w));
        ((ushort4*)dst)[i] = o;
    }
}

// fp32 [1024][1024] -> bf16 transposed [1024][1024]
__global__ void cvt_T(const float* __restrict__ src, ushort* __restrict__ dst) {
    __shared__ float t[32][33];
    const int tx = threadIdx.x, ty = threadIdx.y;
    const int c0 = blockIdx.x * 32, r0 = blockIdx.y * 32;
    for (int i = ty; i < 32; i += 8) t[i][tx] = src[(size_t)(r0 + i) * 1024 + c0 + tx];
    __syncthreads();
    for (int i = ty; i < 32; i += 8) dst[(size_t)(c0 + i) * 1024 + r0 + tx] = f2bf(t[tx][i]);
}

// ---------------- GEMM body: C[4096,1024] = A @ Bt^T, bias, scale ----------------
// 128x128 tile, BK=32, 4 waves, 2-phase LDS double-buffer (stage t+1 || compute t).

template<bool BF16OUT>
__device__ __forceinline__ void gemm_body(
    const ushort* __restrict__ A, const ushort* __restrict__ Bt,
    const float* __restrict__ bias, void* __restrict__ Cout,
    ushort* __restrict__ vpt, float scale, int bM, int bN)
{
    __shared__ ushort As[2][128 * 32];
    __shared__ ushort Bs[2][128 * 32];
    const int tid = threadIdx.x;
    const int lane = tid & 63, w = tid >> 6;
    const int l15 = lane & 15, lg = lane >> 4;
    const int wr = w >> 1, wc = w & 1;

    const ushort* Ag = A + (size_t)bM * 128 * 1024;
    const ushort* Bg = Bt + (size_t)bN * 128 * 1024;
    const int r0 = w * 32 + (lane >> 2);
    const int cc = (lane & 3) * 8;

    auto STAGE = [&](int buf, int kt) {
        const int kk = kt * 32;
#pragma unroll
        for (int i = 0; i < 2; ++i) {
            const int row = r0 + i * 16;
            const int c = w * 2 + i;
            gld_lds16(Ag + (size_t)row * 1024 + kk + cc, &As[buf][c * 512]);
            gld_lds16(Bg + (size_t)row * 1024 + kk + cc, &Bs[buf][c * 512]);
        }
    };

    f32x4 acc[4][4];
#pragma unroll
    for (int m = 0; m < 4; ++m)
#pragma unroll
        for (int n = 0; n < 4; ++n) acc[m][n] = (f32x4){0.f, 0.f, 0.f, 0.f};

    STAGE(0, 0);
    __syncthreads();
    int cur = 0;
    for (int kt = 0; kt < 32; ++kt) {
        if (kt < 31) STAGE(cur ^ 1, kt + 1);
        bfrag aF[4], bF[4];
#pragma unroll
        for (int m = 0; m < 4; ++m) aF[m] = *(const bfrag*)&As[cur][(wr * 64 + m * 16 + l15) * 32 + lg * 8];
#pragma unroll
        for (int n = 0; n < 4; ++n) bF[n] = *(const bfrag*)&Bs[cur][(wc * 64 + n * 16 + l15) * 32 + lg * 8];
        __builtin_amdgcn_s_setprio(1);
#pragma unroll
        for (int m = 0; m < 4; ++m)
#pragma unroll
            for (int n = 0; n < 4; ++n)
                acc[m][n] = __builtin_amdgcn_mfma_f32_16x16x32_bf16(aF[m], bF[n], acc[m][n], 0, 0, 0);
        __builtin_amdgcn_s_setprio(0);
        if (kt < 31) {
            __syncthreads();
            cur ^= 1;
        }
    }

#pragma unroll
    for (int m = 0; m < 4; ++m)
#pragma unroll
        for (int n = 0; n < 4; ++n) {
            const int gcol = bN * 128 + wc * 64 + n * 16 + l15;
            const float bv = bias[gcol];
#pragma unroll
            for (int j = 0; j < 4; ++j) {
                const int grow = bM * 128 + wr * 64 + m * 16 + lg * 4 + j;
                const float val = (acc[m][n][j] + bv) * scale;
                if constexpr (BF16OUT) {
                    ((ushort*)Cout)[(size_t)grow * 1024 + gcol] = f2bf(val);
                    if (vpt) {
                        // V^T per head, s-index bit2<->bit3 swapped within each 16-block
                        // (matches attention's exchange-free P packing).
                        const int b_ = grow >> 11, s_ = grow & 2047;
                        const int h_ = gcol >> 6, d_ = gcol & 63;
                        const int s2 = (s_ & ~15) | (s_ & 3) | ((s_ >> 1) & 4) | ((s_ << 1) & 8);
                        vpt[(size_t)((b_ * 16 + h_) * 64 + d_) * 2048 + s2] = f2bf(val);
                    }
                } else {
                    ((float*)Cout)[(size_t)grow * 1024 + gcol] = val;
                }
            }
        }
}

// q-proj and v-proj batched: grid.z = 0 -> q, 1 -> v (doubles blocks in flight)
__global__ __launch_bounds__(256) void gemm_qv(
    const ushort* __restrict__ Aq, const ushort* __restrict__ Wq, const float* __restrict__ bq, ushort* __restrict__ Cq,
    const ushort* __restrict__ Av, const ushort* __restrict__ Wv, const float* __restrict__ bv, ushort* __restrict__ Cv,
    ushort* __restrict__ vpt, float qscale)
{
    const int z = blockIdx.z;
    gemm_body<true>(z ? Av : Aq, z ? Wv : Wq, z ? bv : bq, z ? (void*)Cv : (void*)Cq,
                    z ? vpt : nullptr, z ? 1.0f : qscale, blockIdx.y, blockIdx.x);
}

__global__ __launch_bounds__(256) void gemm_o(
    const ushort* __restrict__ A, const ushort* __restrict__ Bt,
    const float* __restrict__ bias, float* __restrict__ Cout)
{
    gemm_body<false>(A, Bt, bias, Cout, nullptr, 1.0f, blockIdx.y, blockIdx.x);
}

// ---------------- flash attention, swapped-operand 32x32 MFMA, reg-prefetch pipeline ----------------
// QP: bf16 [4096][1024] pre-scaled by 0.125*log2e. VP: bf16 [4096][1024] (keys AND values).
// VPT: bf16 [32][64][2048] per-head V^T with sigma(bit2<->bit3)-permuted s within 16-blocks.
// AO: bf16 [4096][1024].
// grid (32 bh, 16 qt)  — bh fast => 16 q-tile blocks of one head are 32 apart
// in linear id => same XCD => per-XCD L2 serves the K re-reads.
// Per kt: issue V(kt) + K(kt+1) loads first, consume K(kt) from registers.

__global__ __launch_bounds__(256, 2) void attn_kernel(
    const ushort* __restrict__ QP, const ushort* __restrict__ VP,
    const ushort* __restrict__ VPT, ushort* __restrict__ AO)
{
    const int tid = threadIdx.x;
    const int w = tid >> 6, lane = tid & 63;
    const int l31 = lane & 31, hi = lane >> 5;
    const int bh = blockIdx.x, qt = blockIdx.y;
    const int b = bh >> 4, h = bh & 15;
    const int qrow0 = qt * 128 + w * 32;

    const ushort* Qp = QP + ((size_t)(b * 2048 + qrow0 + l31)) * 1024 + h * 64 + hi * 8;
    const ushort* Kp = VP + ((size_t)(b * 2048 + l31)) * 1024 + h * 64 + hi * 8;
    const ushort* Vt = VPT + (size_t)bh * 64 * 2048 + (size_t)l31 * 2048 + hi * 8;

    // Q fragments (B-operand): lane holds Q[q=l31][ds*16 + 8*hi + t]
    bfrag qB[4];
#pragma unroll
    for (int ds = 0; ds < 4; ++ds) qB[ds] = *(const bfrag*)(Qp + ds * 16);

    f32x16 O0, O1;
#pragma unroll
    for (int r = 0; r < 16; ++r) { O0[r] = 0.f; O1[r] = 0.f; }
    float mrun = -1e30f, lrun = 0.f;

    // current K fragments (kt=0)
    bfrag kC0[4], kC1[4], kN0[4], kN1[4];
#pragma unroll
    for (int ds = 0; ds < 4; ++ds) {
        kC0[ds] = *(const bfrag*)(Kp + ds * 16);
        kC1[ds] = *(const bfrag*)(Kp + 32 * 1024 + ds * 16);
    }

    auto STEP = [&](bfrag (&c0)[4], bfrag (&c1)[4], bfrag (&n0)[4], bfrag (&n1)[4], int kt) {
        // issue V(kt) loads
        const ushort* Vkt = Vt + kt * 64;
        bfrag vF0[4], vF1[4];
#pragma unroll
        for (int ds = 0; ds < 4; ++ds) {
            vF0[ds] = *(const bfrag*)(Vkt + ds * 16);
            vF1[ds] = *(const bfrag*)(Vkt + 65536 + ds * 16);
        }
        // issue K(kt+1) loads
        const int ktn = (kt + 1 < 32) ? kt + 1 : 31;
        const ushort* Ktn = Kp + (size_t)(ktn * 64) * 1024;
#pragma unroll
        for (int ds = 0; ds < 4; ++ds) {
            n0[ds] = *(const bfrag*)(Ktn + ds * 16);
            n1[ds] = *(const bfrag*)(Ktn + 32 * 1024 + ds * 16);
        }

        // QK^T with current K (loaded one step ago)
        f32x16 S0, S1;
#pragma unroll
        for (int r = 0; r < 16; ++r) { S0[r] = 0.f; S1[r] = 0.f; }
        __builtin_amdgcn_s_setprio(1);
#pragma unroll
        for (int ds = 0; ds < 4; ++ds) S0 = mfma32(c0[ds], qB[ds], S0);
#pragma unroll
        for (int ds = 0; ds < 4; ++ds) S1 = mfma32(c1[ds], qB[ds], S1);
        __builtin_amdgcn_s_setprio(0);

        // online softmax, in-register, exp2 domain
        float mx[8];
#pragma unroll
        for (int i = 0; i < 8; ++i)
            mx[i] = fmaxf(fmaxf(S0[i], S0[i + 8]), fmaxf(S1[i], S1[i + 8]));
        const float m4 = fmaxf(fmaxf(mx[0], mx[1]), fmaxf(mx[2], mx[3]));
        const float m5 = fmaxf(fmaxf(mx[4], mx[5]), fmaxf(mx[6], mx[7]));
        float pmax = fmaxf(m4, m5);
        pmax = fmaxf(pmax, __shfl_xor(pmax, 32));

        if (!__all(pmax - mrun <= 8.0f)) {   // defer-max (T13)
            const float mnew = fmaxf(mrun, pmax);
            const float rsc = __builtin_amdgcn_exp2f(mrun - mnew);
            mrun = mnew;
            lrun *= rsc;
#pragma unroll
            for (int r = 0; r < 16; ++r) { O0[r] *= rsc; O1[r] *= rsc; }
        }

        float p[32];
#pragma unroll
        for (int r = 0; r < 16; ++r) {
            p[r]      = __builtin_amdgcn_exp2f(S0[r] - mrun);
            p[16 + r] = __builtin_amdgcn_exp2f(S1[r] - mrun);
        }
        float s8[8];
#pragma unroll
        for (int i = 0; i < 8; ++i) s8[i] = (p[i] + p[i + 8]) + (p[i + 16] + p[i + 24]);
        float ssum = ((s8[0] + s8[1]) + (s8[2] + s8[3])) + ((s8[4] + s8[5]) + (s8[6] + s8[7]));
        ssum += __shfl_xor(ssum, 32);
        lrun += ssum;

        // pack P -> bf16 B-fragments, exchange-free (kv permuted by sigma; VPT matches)
        bfrag pB[4];
#pragma unroll
        for (int c = 0; c < 4; ++c) {
            union { v4u u; bfrag f; } cv;
#pragma unroll
            for (int wd = 0; wd < 4; ++wd)
                cv.u[wd] = pack_bf16x2(p[8 * c + 2 * wd], p[8 * c + 2 * wd + 1]);
            pB[c] = cv.f;
        }

        // PV (swapped): O^T += V^T-frag x P^T-frag
        __builtin_amdgcn_s_setprio(1);
#pragma unroll
        for (int c = 0; c < 4; ++c) O0 = mfma32(vF0[c], pB[c], O0);
#pragma unroll
        for (int c = 0; c < 4; ++c) O1 = mfma32(vF1[c], pB[c], O1);
        __builtin_amdgcn_s_setprio(0);
    };

#pragma unroll 1
    for (int t2 = 0; t2 < 16; ++t2) {
        STEP(kC0, kC1, kN0, kN1, 2 * t2);
        STEP(kN0, kN1, kC0, kC1, 2 * t2 + 1);
    }

    // epilogue: O^T / l -> AO[q][h*64+d], 8B packed stores
    const float inv = 1.f / lrun;
    ushort* Ao = AO + (size_t)(b * 2048 + qrow0 + l31) * 1024 + h * 64 + hi * 4;
#pragma unroll
    for (int t = 0; t < 2; ++t) {
#pragma unroll
        for (int g = 0; g < 4; ++g) {
            const float e0 = (t ? O1[4 * g + 0] : O0[4 * g + 0]) * inv;
            const float e1 = (t ? O1[4 * g + 1] : O0[4 * g + 1]) * inv;
            const float e2 = (t ? O1[4 * g + 2] : O0[4 * g + 2]) * inv;
            const float e3 = (t ? O1[4 * g + 3] : O0[4 * g + 3]) * inv;
            v2u pk = (v2u){pack_bf16x2(e0, e1), pack_bf16x2(e2, e3)};
            *(v2u*)(Ao + t * 32 + g * 8) = pk;
        }
    }
}

// ---------------- launcher ----------------

extern "C" void kernel_launch(void* const* d_in, const int* in_sizes, int n_in,
                              void* d_out, int out_size, void* d_ws, size_t ws_size,
                              hipStream_t stream) {
    (void)in_sizes; (void)n_in; (void)out_size; (void)ws_size;
    const float* q  = (const float*)d_in[0];
    const float* v  = (const float*)d_in[2];
    const float* Wq = (const float*)d_in[3];
    const float* bq = (const float*)d_in[4];
    const float* Wv = (const float*)d_in[7];
    const float* bv = (const float*)d_in[8];
    const float* Wo = (const float*)d_in[9];
    const float* bo = (const float*)d_in[10];
    float* out = (float*)d_out;
    char* ws = (char*)d_ws;
    const size_t MB = 1ull << 20;
    ushort* qbf = (ushort*)(ws + 0);         // 8MB (reused as AO)
    ushort* vbf = (ushort*)(ws + 8 * MB);    // 8MB
    ushort* WqT = (ushort*)(ws + 16 * MB);   // 2MB
    ushort* WvT = (ushort*)(ws + 18 * MB);   // 2MB
    ushort* WoT = (ushort*)(ws + 20 * MB);   // 2MB
    ushort* QPb = (ushort*)(ws + 22 * MB);   // 8MB
    ushort* VPb = (ushort*)(ws + 30 * MB);   // 8MB
    ushort* VPT = (ushort*)(ws + 38 * MB);   // 8MB
    ushort* AO  = qbf;                        // alias: qbf dead after q-proj GEMM

    cvt_bf16<<<4096, 256, 0, stream>>>(q, qbf, 1048576);
    cvt_bf16<<<4096, 256, 0, stream>>>(v, vbf, 1048576);
    dim3 tb(32, 8);
    cvt_T<<<dim3(32, 32), tb, 0, stream>>>(Wq, WqT);
    cvt_T<<<dim3(32, 32), tb, 0, stream>>>(Wv, WvT);
    cvt_T<<<dim3(32, 32), tb, 0, stream>>>(Wo, WoT);

    const float qscale = 0.125f * 1.44269504088896340736f;
    gemm_qv<<<dim3(8, 32, 2), 256, 0, stream>>>(qbf, WqT, bq, QPb,
                                                vbf, WvT, bv, VPb, VPT, qscale);
    attn_kernel<<<dim3(32, 16), 256, 0, stream>>>(QPb, VPb, VPT, AO);
    gemm_o<<<dim3(8, 32), 256, 0, stream>>>(AO, WoT, bo, out);
}

// Round 5
// 144.681 us; speedup vs baseline: 1.8906x; 1.4360x over previous
//
#include <hip/hip_runtime.h>
#include <hip/hip_bf16.h>

using bfrag  = __attribute__((ext_vector_type(8))) __bf16;
using f32x4  = __attribute__((ext_vector_type(4))) float;
using f32x16 = __attribute__((ext_vector_type(16))) float;
using v4u    = __attribute__((ext_vector_type(4))) unsigned int;
using v2u    = __attribute__((ext_vector_type(2))) unsigned int;

__device__ __forceinline__ ushort f2bf(float f) {
    union { float f; unsigned u; } c; c.f = f;
    return (ushort)((c.u + 0x7fffu + ((c.u >> 16) & 1u)) >> 16);
}

__device__ __forceinline__ unsigned pack_bf16x2(float lo, float hi) {
    union { __hip_bfloat162 h; unsigned u; } c;
    c.h = __float22bfloat162_rn(make_float2(lo, hi));   // lo -> low ushort, hi -> high
    return c.u;
}

__device__ __forceinline__ void gld_lds16(const ushort* g, ushort* l) {
    __builtin_amdgcn_global_load_lds(
        (const __attribute__((address_space(1))) void*)g,
        (__attribute__((address_space(3))) void*)l, 16, 0, 0);
}

__device__ __forceinline__ f32x16 mfma32(bfrag a, bfrag b, f32x16 c) {
    return __builtin_amdgcn_mfma_f32_32x32x16_bf16(a, b, c, 0, 0, 0);
}

// ---------------- conversion kernels ----------------

__global__ void cvt_bf16(const float* __restrict__ src, ushort* __restrict__ dst, int n4) {
    int i = blockIdx.x * blockDim.x + threadIdx.x;
    if (i < n4) {
        float4 f = ((const float4*)src)[i];
        ushort4 o = make_ushort4(f2bf(f.x), f2bf(f.y), f2bf(f.z), f2bf(f.w));
        ((ushort4*)dst)[i] = o;
    }
}

// fp32 [1024][1024] -> bf16 transposed [1024][1024]
__global__ void cvt_T(const float* __restrict__ src, ushort* __restrict__ dst) {
    __shared__ float t[32][33];
    const int tx = threadIdx.x, ty = threadIdx.y;
    const int c0 = blockIdx.x * 32, r0 = blockIdx.y * 32;
    for (int i = ty; i < 32; i += 8) t[i][tx] = src[(size_t)(r0 + i) * 1024 + c0 + tx];
    __syncthreads();
    for (int i = ty; i < 32; i += 8) dst[(size_t)(c0 + i) * 1024 + r0 + tx] = f2bf(t[tx][i]);
}

// ---------------- GEMM body: C[4096,1024] = A @ Bt^T, bias, scale ----------------
// 128x128 tile, BK=32, 4 waves, 2-phase LDS double-buffer (stage t+1 || compute t).

template<bool BF16OUT>
__device__ __forceinline__ void gemm_body(
    const ushort* __restrict__ A, const ushort* __restrict__ Bt,
    const float* __restrict__ bias, void* __restrict__ Cout,
    ushort* __restrict__ vpt, float scale, int bM, int bN)
{
    __shared__ ushort As[2][128 * 32];
    __shared__ ushort Bs[2][128 * 32];
    const int tid = threadIdx.x;
    const int lane = tid & 63, w = tid >> 6;
    const int l15 = lane & 15, lg = lane >> 4;
    const int wr = w >> 1, wc = w & 1;

    const ushort* Ag = A + (size_t)bM * 128 * 1024;
    const ushort* Bg = Bt + (size_t)bN * 128 * 1024;
    const int r0 = w * 32 + (lane >> 2);
    const int cc = (lane & 3) * 8;

    auto STAGE = [&](int buf, int kt) {
        const int kk = kt * 32;
#pragma unroll
        for (int i = 0; i < 2; ++i) {
            const int row = r0 + i * 16;
            const int c = w * 2 + i;
            gld_lds16(Ag + (size_t)row * 1024 + kk + cc, &As[buf][c * 512]);
            gld_lds16(Bg + (size_t)row * 1024 + kk + cc, &Bs[buf][c * 512]);
        }
    };

    f32x4 acc[4][4];
#pragma unroll
    for (int m = 0; m < 4; ++m)
#pragma unroll
        for (int n = 0; n < 4; ++n) acc[m][n] = (f32x4){0.f, 0.f, 0.f, 0.f};

    STAGE(0, 0);
    __syncthreads();
    int cur = 0;
    for (int kt = 0; kt < 32; ++kt) {
        if (kt < 31) STAGE(cur ^ 1, kt + 1);
        bfrag aF[4], bF[4];
#pragma unroll
        for (int m = 0; m < 4; ++m) aF[m] = *(const bfrag*)&As[cur][(wr * 64 + m * 16 + l15) * 32 + lg * 8];
#pragma unroll
        for (int n = 0; n < 4; ++n) bF[n] = *(const bfrag*)&Bs[cur][(wc * 64 + n * 16 + l15) * 32 + lg * 8];
        __builtin_amdgcn_s_setprio(1);
#pragma unroll
        for (int m = 0; m < 4; ++m)
#pragma unroll
            for (int n = 0; n < 4; ++n)
                acc[m][n] = __builtin_amdgcn_mfma_f32_16x16x32_bf16(aF[m], bF[n], acc[m][n], 0, 0, 0);
        __builtin_amdgcn_s_setprio(0);
        if (kt < 31) {
            __syncthreads();
            cur ^= 1;
        }
    }

#pragma unroll
    for (int m = 0; m < 4; ++m)
#pragma unroll
        for (int n = 0; n < 4; ++n) {
            const int gcol = bN * 128 + wc * 64 + n * 16 + l15;
            const float bv = bias[gcol];
#pragma unroll
            for (int j = 0; j < 4; ++j) {
                const int grow = bM * 128 + wr * 64 + m * 16 + lg * 4 + j;
                const float val = (acc[m][n][j] + bv) * scale;
                if constexpr (BF16OUT) {
                    ((ushort*)Cout)[(size_t)grow * 1024 + gcol] = f2bf(val);
                    if (vpt) {
                        // V^T per head, s-index bit2<->bit3 swapped within each 16-block
                        // (matches attention's exchange-free P packing).
                        const int b_ = grow >> 11, s_ = grow & 2047;
                        const int h_ = gcol >> 6, d_ = gcol & 63;
                        const int s2 = (s_ & ~15) | (s_ & 3) | ((s_ >> 1) & 4) | ((s_ << 1) & 8);
                        vpt[(size_t)((b_ * 16 + h_) * 64 + d_) * 2048 + s2] = f2bf(val);
                    }
                } else {
                    ((float*)Cout)[(size_t)grow * 1024 + gcol] = val;
                }
            }
        }
}

// q-proj and v-proj batched: grid.z = 0 -> q, 1 -> v (doubles blocks in flight)
__global__ __launch_bounds__(256) void gemm_qv(
    const ushort* __restrict__ Aq, const ushort* __restrict__ Wq, const float* __restrict__ bq, ushort* __restrict__ Cq,
    const ushort* __restrict__ Av, const ushort* __restrict__ Wv, const float* __restrict__ bv, ushort* __restrict__ Cv,
    ushort* __restrict__ vpt, float qscale)
{
    const int z = blockIdx.z;
    gemm_body<true>(z ? Av : Aq, z ? Wv : Wq, z ? bv : bq, z ? (void*)Cv : (void*)Cq,
                    z ? vpt : nullptr, z ? 1.0f : qscale, blockIdx.y, blockIdx.x);
}

__global__ __launch_bounds__(256) void gemm_o(
    const ushort* __restrict__ A, const ushort* __restrict__ Bt,
    const float* __restrict__ bias, float* __restrict__ Cout)
{
    gemm_body<false>(A, Bt, bias, Cout, nullptr, 1.0f, blockIdx.y, blockIdx.x);
}

// ---------------- flash attention: LDS-shared coalesced K/V tiles ----------------
// QP: bf16 [4096][1024] pre-scaled by 0.125*log2e. VP: bf16 [4096][1024] (keys AND values).
// VPT: bf16 [32][64][2048] per-head V^T with sigma(bit2<->bit3)-permuted s within 16-blocks.
// AO: bf16 [4096][1024].
// grid (32 bh, 16 qt): bh fast => q-tile blocks of one head land on the same XCD (L2 reuse).
// Per kt: all 4 waves share one 64x64 K-tile and one 64x64 V^T-tile staged into LDS
// via global_load_lds with ROW-CONTIGUOUS source (coalesced) and st_16x32 XOR swizzle
// applied through the per-lane SOURCE address (linear LDS dest), read back swizzled.
// LDS layout: tile elem (r,c) at byte r*128 + ((c*2) ^ ((r&7)<<4)).

__global__ __launch_bounds__(256, 4) void attn_kernel(
    const ushort* __restrict__ QP, const ushort* __restrict__ VP,
    const ushort* __restrict__ VPT, ushort* __restrict__ AO)
{
    __shared__ ushort Ks[2][4096];
    __shared__ ushort Vs[2][4096];
    const int tid = threadIdx.x;
    const int w = tid >> 6, lane = tid & 63;
    const int l31 = lane & 31, hi = lane >> 5;
    const int bh = blockIdx.x, qt = blockIdx.y;
    const int b = bh >> 4, h = bh & 15;
    const int qrow0 = qt * 128 + w * 32;

    // staging decode: thread stages 16B chunks; linear LDS offset (kb*1024 + lane*16)B
    // corresponds to tile (r = kb*8 + lane/8, c = ((lane&7) ^ ((lane>>3)&7)) * 8).
    const int sr = lane >> 3;                    // row within 8-row block
    const int sc = ((lane & 7) ^ sr) * 8;        // inverse-swizzled column (elements)
    const ushort* Kg = VP + (size_t)(b * 2048) * 1024 + h * 64 + sc;
    const ushort* Vg = VPT + (size_t)bh * 131072 + sc;

    auto STAGE = [&](int buf, int kt) {
#pragma unroll
        for (int i = 0; i < 2; ++i) {
            const int kb = w * 2 + i;            // wave-uniform kilobyte block 0..7
            const int r = kb * 8 + sr;
            gld_lds16(Kg + (size_t)(kt * 64 + r) * 1024, &Ks[buf][kb * 512]);
            gld_lds16(Vg + (size_t)r * 2048 + kt * 64, &Vs[buf][kb * 512]);
        }
    };

    // Q fragments (B-operand), one-time scattered load: Q[q=l31][ds*16 + 8*hi + t]
    const ushort* Qp = QP + ((size_t)(b * 2048 + qrow0 + l31)) * 1024 + h * 64 + hi * 8;
    bfrag qB[4];
#pragma unroll
    for (int ds = 0; ds < 4; ++ds) qB[ds] = *(const bfrag*)(Qp + ds * 16);

    f32x16 O0, O1;
#pragma unroll
    for (int r = 0; r < 16; ++r) { O0[r] = 0.f; O1[r] = 0.f; }
    float mrun = -1e30f, lrun = 0.f;

    const int swz = (l31 & 7) << 4;              // row-XOR for fragment reads
    const int cA = hi * 16;                      // byte col base: hi*8 elems

    STAGE(0, 0);
    __syncthreads();
    int cur = 0;

#pragma unroll 1
    for (int kt = 0; kt < 32; ++kt) {
        if (kt < 31) STAGE(cur ^ 1, kt + 1);
        const ushort* Kb_ = Ks[cur];
        const ushort* Vb_ = Vs[cur];

        // K fragments: rows l31 / l31+32 ((r&7) identical => same swz)
        bfrag kA0[4], kA1[4];
#pragma unroll
        for (int ds = 0; ds < 4; ++ds) {
            kA0[ds] = *(const bfrag*)&Kb_[(l31 * 128 + ((ds * 32 + cA) ^ swz)) >> 1];
            kA1[ds] = *(const bfrag*)&Kb_[((l31 + 32) * 128 + ((ds * 32 + cA) ^ swz)) >> 1];
        }

        f32x16 S0, S1;
#pragma unroll
        for (int r = 0; r < 16; ++r) { S0[r] = 0.f; S1[r] = 0.f; }
        __builtin_amdgcn_s_setprio(1);
#pragma unroll
        for (int ds = 0; ds < 4; ++ds) S0 = mfma32(kA0[ds], qB[ds], S0);
#pragma unroll
        for (int ds = 0; ds < 4; ++ds) S1 = mfma32(kA1[ds], qB[ds], S1);
        __builtin_amdgcn_s_setprio(0);

        // ---- online softmax, in-register, exp2 domain ----
        float mx[8];
#pragma unroll
        for (int i = 0; i < 8; ++i)
            mx[i] = fmaxf(fmaxf(S0[i], S0[i + 8]), fmaxf(S1[i], S1[i + 8]));
        const float m4 = fmaxf(fmaxf(mx[0], mx[1]), fmaxf(mx[2], mx[3]));
        const float m5 = fmaxf(fmaxf(mx[4], mx[5]), fmaxf(mx[6], mx[7]));
        float pmax = fmaxf(m4, m5);
        pmax = fmaxf(pmax, __shfl_xor(pmax, 32));

        if (!__all(pmax - mrun <= 8.0f)) {   // defer-max (T13)
            const float mnew = fmaxf(mrun, pmax);
            const float rsc = __builtin_amdgcn_exp2f(mrun - mnew);
            mrun = mnew;
            lrun *= rsc;
#pragma unroll
            for (int r = 0; r < 16; ++r) { O0[r] *= rsc; O1[r] *= rsc; }
        }

        float p[32];
#pragma unroll
        for (int r = 0; r < 16; ++r) {
            p[r]      = __builtin_amdgcn_exp2f(S0[r] - mrun);
            p[16 + r] = __builtin_amdgcn_exp2f(S1[r] - mrun);
        }
        float s8[8];
#pragma unroll
        for (int i = 0; i < 8; ++i) s8[i] = (p[i] + p[i + 8]) + (p[i + 16] + p[i + 24]);
        float ssum = ((s8[0] + s8[1]) + (s8[2] + s8[3])) + ((s8[4] + s8[5]) + (s8[6] + s8[7]));
        ssum += __shfl_xor(ssum, 32);
        lrun += ssum;

        // pack P -> bf16 B-fragments, exchange-free (kv permuted by sigma; VPT matches)
        bfrag pB[4];
#pragma unroll
        for (int c = 0; c < 4; ++c) {
            union { v4u u; bfrag f; } cv;
#pragma unroll
            for (int wd = 0; wd < 4; ++wd)
                cv.u[wd] = pack_bf16x2(p[8 * c + 2 * wd], p[8 * c + 2 * wd + 1]);
            pB[c] = cv.f;
        }

        // PV (swapped): O^T += V^T-frag x P^T-frag; V frags from LDS
        __builtin_amdgcn_s_setprio(1);
#pragma unroll
        for (int c = 0; c < 4; ++c)
            O0 = mfma32(*(const bfrag*)&Vb_[(l31 * 128 + ((c * 32 + cA) ^ swz)) >> 1], pB[c], O0);
#pragma unroll
        for (int c = 0; c < 4; ++c)
            O1 = mfma32(*(const bfrag*)&Vb_[((l31 + 32) * 128 + ((c * 32 + cA) ^ swz)) >> 1], pB[c], O1);
        __builtin_amdgcn_s_setprio(0);

        __syncthreads();   // staged next tile landed (vmcnt drained) + all waves done with cur
        cur ^= 1;
    }

    // epilogue: O^T / l -> AO[q][h*64+d], 8B packed stores
    const float inv = 1.f / lrun;
    ushort* Ao = AO + (size_t)(b * 2048 + qrow0 + l31) * 1024 + h * 64 + hi * 4;
#pragma unroll
    for (int t = 0; t < 2; ++t) {
#pragma unroll
        for (int g = 0; g < 4; ++g) {
            const float e0 = (t ? O1[4 * g + 0] : O0[4 * g + 0]) * inv;
            const float e1 = (t ? O1[4 * g + 1] : O0[4 * g + 1]) * inv;
            const float e2 = (t ? O1[4 * g + 2] : O0[4 * g + 2]) * inv;
            const float e3 = (t ? O1[4 * g + 3] : O0[4 * g + 3]) * inv;
            v2u pk = (v2u){pack_bf16x2(e0, e1), pack_bf16x2(e2, e3)};
            *(v2u*)(Ao + t * 32 + g * 8) = pk;
        }
    }
}

// ---------------- launcher ----------------

extern "C" void kernel_launch(void* const* d_in, const int* in_sizes, int n_in,
                              void* d_out, int out_size, void* d_ws, size_t ws_size,
                              hipStream_t stream) {
    (void)in_sizes; (void)n_in; (void)out_size; (void)ws_size;
    const float* q  = (const float*)d_in[0];
    const float* v  = (const float*)d_in[2];
    const float* Wq = (const float*)d_in[3];
    const float* bq = (const float*)d_in[4];
    const float* Wv = (const float*)d_in[7];
    const float* bv = (const float*)d_in[8];
    const float* Wo = (const float*)d_in[9];
    const float* bo = (const float*)d_in[10];
    float* out = (float*)d_out;
    char* ws = (char*)d_ws;
    const size_t MB = 1ull << 20;
    ushort* qbf = (ushort*)(ws + 0);         // 8MB (reused as AO)
    ushort* vbf = (ushort*)(ws + 8 * MB);    // 8MB
    ushort* WqT = (ushort*)(ws + 16 * MB);   // 2MB
    ushort* WvT = (ushort*)(ws + 18 * MB);   // 2MB
    ushort* WoT = (ushort*)(ws + 20 * MB);   // 2MB
    ushort* QPb = (ushort*)(ws + 22 * MB);   // 8MB
    ushort* VPb = (ushort*)(ws + 30 * MB);   // 8MB
    ushort* VPT = (ushort*)(ws + 38 * MB);   // 8MB
    ushort* AO  = qbf;                        // alias: qbf dead after q-proj GEMM

    cvt_bf16<<<4096, 256, 0, stream>>>(q, qbf, 1048576);
    cvt_bf16<<<4096, 256, 0, stream>>>(v, vbf, 1048576);
    dim3 tb(32, 8);
    cvt_T<<<dim3(32, 32), tb, 0, stream>>>(Wq, WqT);
    cvt_T<<<dim3(32, 32), tb, 0, stream>>>(Wv, WvT);
    cvt_T<<<dim3(32, 32), tb, 0, stream>>>(Wo, WoT);

    const float qscale = 0.125f * 1.44269504088896340736f;
    gemm_qv<<<dim3(8, 32, 2), 256, 0, stream>>>(qbf, WqT, bq, QPb,
                                                vbf, WvT, bv, VPb, VPT, qscale);
    attn_kernel<<<dim3(32, 16), 256, 0, stream>>>(QPb, VPb, VPT, AO);
    gemm_o<<<dim3(8, 32), 256, 0, stream>>>(AO, WoT, bo, out);
}

// Round 7
// 135.966 us; speedup vs baseline: 2.0117x; 1.0641x over previous
//
#include <hip/hip_runtime.h>
#include <hip/hip_bf16.h>

using bfrag  = __attribute__((ext_vector_type(8))) __bf16;
using f32x4  = __attribute__((ext_vector_type(4))) float;
using f32x16 = __attribute__((ext_vector_type(16))) float;
using v4u    = __attribute__((ext_vector_type(4))) unsigned int;
using v2u    = __attribute__((ext_vector_type(2))) unsigned int;

__device__ __forceinline__ ushort f2bf(float f) {
    union { float f; unsigned u; } c; c.f = f;
    return (ushort)((c.u + 0x7fffu + ((c.u >> 16) & 1u)) >> 16);
}

__device__ __forceinline__ unsigned pack_bf16x2(float lo, float hi) {
    union { __hip_bfloat162 h; unsigned u; } c;
    c.h = __float22bfloat162_rn(make_float2(lo, hi));   // lo -> low ushort, hi -> high
    return c.u;
}

__device__ __forceinline__ void gld_lds16(const ushort* g, ushort* l) {
    __builtin_amdgcn_global_load_lds(
        (const __attribute__((address_space(1))) void*)g,
        (__attribute__((address_space(3))) void*)l, 16, 0, 0);
}

__device__ __forceinline__ f32x16 mfma32(bfrag a, bfrag b, f32x16 c) {
    return __builtin_amdgcn_mfma_f32_32x32x16_bf16(a, b, c, 0, 0, 0);
}

// ---------------- conversion kernels (fused) ----------------

__global__ void cvt_bf16_2(const float* __restrict__ a, ushort* __restrict__ da,
                           const float* __restrict__ b, ushort* __restrict__ db, int n4) {
    int i = blockIdx.x * blockDim.x + threadIdx.x;
    const float* s; ushort* d;
    if (i < n4) { s = a; d = da; } else { s = b; d = db; i -= n4; }
    float4 f = ((const float4*)s)[i];
    ((ushort4*)d)[i] = make_ushort4(f2bf(f.x), f2bf(f.y), f2bf(f.z), f2bf(f.w));
}

// fp32 [1024][1024] -> bf16 transposed, 3 weight matrices in one dispatch (z=0..2)
__global__ void cvt_T3(const float* __restrict__ s0, ushort* __restrict__ d0,
                       const float* __restrict__ s1, ushort* __restrict__ d1,
                       const float* __restrict__ s2, ushort* __restrict__ d2) {
    __shared__ float t[32][33];
    const int z = blockIdx.z;
    const float* src = z == 0 ? s0 : z == 1 ? s1 : s2;
    ushort* dst = z == 0 ? d0 : z == 1 ? d1 : d2;
    const int tx = threadIdx.x, ty = threadIdx.y;
    const int c0 = blockIdx.x * 32, r0 = blockIdx.y * 32;
    for (int i = ty; i < 32; i += 8) t[i][tx] = src[(size_t)(r0 + i) * 1024 + c0 + tx];
    __syncthreads();
    for (int i = ty; i < 32; i += 8) dst[(size_t)(c0 + i) * 1024 + r0 + tx] = f2bf(t[tx][i]);
}

// ---------------- GEMM body: C[4096,1024] = A @ Bt^T, bias, scale ----------------
// 128x128 tile, BK=32, 4 waves, 2-phase LDS double-buffer (stage t+1 || compute t).

template<bool BF16OUT>
__device__ __forceinline__ void gemm_body(
    const ushort* __restrict__ A, const ushort* __restrict__ Bt,
    const float* __restrict__ bias, void* __restrict__ Cout,
    ushort* __restrict__ vpt, float scale, int bM, int bN)
{
    __shared__ ushort As[2][128 * 32];
    __shared__ ushort Bs[2][128 * 32];
    const int tid = threadIdx.x;
    const int lane = tid & 63, w = tid >> 6;
    const int l15 = lane & 15, lg = lane >> 4;
    const int wr = w >> 1, wc = w & 1;

    const ushort* Ag = A + (size_t)bM * 128 * 1024;
    const ushort* Bg = Bt + (size_t)bN * 128 * 1024;
    const int r0 = w * 32 + (lane >> 2);
    const int cc = (lane & 3) * 8;

    auto STAGE = [&](int buf, int kt) {
        const int kk = kt * 32;
#pragma unroll
        for (int i = 0; i < 2; ++i) {
            const int row = r0 + i * 16;
            const int c = w * 2 + i;
            gld_lds16(Ag + (size_t)row * 1024 + kk + cc, &As[buf][c * 512]);
            gld_lds16(Bg + (size_t)row * 1024 + kk + cc, &Bs[buf][c * 512]);
        }
    };

    f32x4 acc[4][4];
#pragma unroll
    for (int m = 0; m < 4; ++m)
#pragma unroll
        for (int n = 0; n < 4; ++n) acc[m][n] = (f32x4){0.f, 0.f, 0.f, 0.f};

    STAGE(0, 0);
    __syncthreads();
    int cur = 0;
    for (int kt = 0; kt < 32; ++kt) {
        if (kt < 31) STAGE(cur ^ 1, kt + 1);
        bfrag aF[4], bF[4];
#pragma unroll
        for (int m = 0; m < 4; ++m) aF[m] = *(const bfrag*)&As[cur][(wr * 64 + m * 16 + l15) * 32 + lg * 8];
#pragma unroll
        for (int n = 0; n < 4; ++n) bF[n] = *(const bfrag*)&Bs[cur][(wc * 64 + n * 16 + l15) * 32 + lg * 8];
        __builtin_amdgcn_s_setprio(1);
#pragma unroll
        for (int m = 0; m < 4; ++m)
#pragma unroll
            for (int n = 0; n < 4; ++n)
                acc[m][n] = __builtin_amdgcn_mfma_f32_16x16x32_bf16(aF[m], bF[n], acc[m][n], 0, 0, 0);
        __builtin_amdgcn_s_setprio(0);
        if (kt < 31) {
            __syncthreads();
            cur ^= 1;
        }
    }

#pragma unroll
    for (int m = 0; m < 4; ++m)
#pragma unroll
        for (int n = 0; n < 4; ++n) {
            const int gcol = bN * 128 + wc * 64 + n * 16 + l15;
            const float bv = bias[gcol];
#pragma unroll
            for (int j = 0; j < 4; ++j) {
                const int grow = bM * 128 + wr * 64 + m * 16 + lg * 4 + j;
                const float val = (acc[m][n][j] + bv) * scale;
                if constexpr (BF16OUT) {
                    ((ushort*)Cout)[(size_t)grow * 1024 + gcol] = f2bf(val);
                    if (vpt) {
                        // V^T per head, s-index bit2<->bit3 swapped within each 16-block
                        // (matches attention's exchange-free P packing).
                        const int b_ = grow >> 11, s_ = grow & 2047;
                        const int h_ = gcol >> 6, d_ = gcol & 63;
                        const int s2 = (s_ & ~15) | (s_ & 3) | ((s_ >> 1) & 4) | ((s_ << 1) & 8);
                        vpt[(size_t)((b_ * 16 + h_) * 64 + d_) * 2048 + s2] = f2bf(val);
                    }
                } else {
                    ((float*)Cout)[(size_t)grow * 1024 + gcol] = val;
                }
            }
        }
}

// q-proj and v-proj batched: grid.z = 0 -> q, 1 -> v (doubles blocks in flight)
__global__ __launch_bounds__(256) void gemm_qv(
    const ushort* __restrict__ Aq, const ushort* __restrict__ Wq, const float* __restrict__ bq, ushort* __restrict__ Cq,
    const ushort* __restrict__ Av, const ushort* __restrict__ Wv, const float* __restrict__ bv, ushort* __restrict__ Cv,
    ushort* __restrict__ vpt, float qscale)
{
    const int z = blockIdx.z;
    gemm_body<true>(z ? Av : Aq, z ? Wv : Wq, z ? bv : bq, z ? (void*)Cv : (void*)Cq,
                    z ? vpt : nullptr, z ? 1.0f : qscale, blockIdx.y, blockIdx.x);
}

__global__ __launch_bounds__(256) void gemm_o(
    const ushort* __restrict__ A, const ushort* __restrict__ Bt,
    const float* __restrict__ bias, float* __restrict__ Cout)
{
    gemm_body<false>(A, Bt, bias, Cout, nullptr, 1.0f, blockIdx.y, blockIdx.x);
}

// ---------------- flash attention: 3-slot LDS ring + cross-kt MFMA/VALU pipeline ----------------
// QP: bf16 [4096][1024] pre-scaled by 0.125*log2e. VP: bf16 [4096][1024] (keys AND values).
// VPT: bf16 [32][64][2048] per-head V^T with sigma(bit2<->bit3)-permuted s within 16-blocks.
// AO: bf16 [4096][1024].
// grid (32 bh, 16 qt): bh fast => q-tile blocks of one head share an XCD (L2 reuse).
// Per step kt: sync -> STAGE(kt+2, slot s2) -> issue QK^T(kt+1) [MFMA] -> softmax(kt)
// [VALU, overlaps MFMA] -> PV(kt) [MFMA]. Scores double-buffered (SA/SB).
// Cross-half reductions use __shfl_xor(,32) — the permlane32_swap asm was WRONG (r2/r6 failures).

__global__ __launch_bounds__(256, 2) void attn_kernel(
    const ushort* __restrict__ QP, const ushort* __restrict__ VP,
    const ushort* __restrict__ VPT, ushort* __restrict__ AO)
{
    __shared__ ushort KV[3][8192];
    const int tid = threadIdx.x;
    const int w = tid >> 6, lane = tid & 63;
    const int l31 = lane & 31, hi = lane >> 5;
    const int bh = blockIdx.x, qt = blockIdx.y;
    const int b = bh >> 4, h = bh & 15;
    const int qrow0 = qt * 128 + w * 32;

    // staging: linear LDS dest, inverse-swizzled global source column
    const int sr = lane >> 3;
    const int sc = ((lane & 7) ^ sr) * 8;
    const ushort* Kg = VP + (size_t)(b * 2048) * 1024 + h * 64 + sc;
    const ushort* Vg = VPT + (size_t)bh * 131072 + sc;

    auto STAGE = [&](int slot, int kt) {
#pragma unroll
        for (int i = 0; i < 2; ++i) {
            const int kb = w * 2 + i;
            const int r = kb * 8 + sr;
            gld_lds16(Kg + (size_t)(kt * 64 + r) * 1024, &KV[slot][kb * 512]);
            gld_lds16(Vg + (size_t)r * 2048 + kt * 64, &KV[slot][4096 + kb * 512]);
        }
    };

    // Q fragments (B-operand): lane holds Q[q=l31][ds*16 + 8*hi + t]
    const ushort* Qp = QP + ((size_t)(b * 2048 + qrow0 + l31)) * 1024 + h * 64 + hi * 8;
    bfrag qB[4];
#pragma unroll
    for (int ds = 0; ds < 4; ++ds) qB[ds] = *(const bfrag*)(Qp + ds * 16);

    f32x16 O0, O1, SA0, SA1, SB0, SB1;
#pragma unroll
    for (int r = 0; r < 16; ++r) { O0[r] = 0.f; O1[r] = 0.f; }
    float mrun = -1e30f, lrun = 0.f;

    const int swz = (l31 & 7) << 4;
    const int cA = hi * 16;

    STAGE(0, 0);
    STAGE(1, 1);
    __syncthreads();

    // prologue: S(0) = QK^T(K0)
    {
        const ushort* Kb_ = KV[0];
        bfrag k0[4], k1[4];
#pragma unroll
        for (int ds = 0; ds < 4; ++ds) {
            k0[ds] = *(const bfrag*)&Kb_[(l31 * 128 + ((ds * 32 + cA) ^ swz)) >> 1];
            k1[ds] = *(const bfrag*)&Kb_[((l31 + 32) * 128 + ((ds * 32 + cA) ^ swz)) >> 1];
        }
#pragma unroll
        for (int r = 0; r < 16; ++r) { SA0[r] = 0.f; SA1[r] = 0.f; }
        __builtin_amdgcn_s_setprio(1);
#pragma unroll
        for (int ds = 0; ds < 4; ++ds) SA0 = mfma32(k0[ds], qB[ds], SA0);
#pragma unroll
        for (int ds = 0; ds < 4; ++ds) SA1 = mfma32(k1[ds], qB[ds], SA1);
        __builtin_amdgcn_s_setprio(0);
    }

    auto STEP = [&](f32x16& Sc0, f32x16& Sc1, f32x16& Sn0, f32x16& Sn1,
                    int kt, int s0, int s1, int s2) {
        if (kt > 0) __syncthreads();            // drains STAGE(kt+1) (issued last step)
        if (kt + 2 < 32) STAGE(s2, kt + 2);     // issue next-next tile (lands during compute)

        // issue QK^T(kt+1) on the MFMA pipe first...
        if (kt + 1 < 32) {
            const ushort* Kb_ = KV[s1];
            bfrag k0[4], k1[4];
#pragma unroll
            for (int ds = 0; ds < 4; ++ds) {
                k0[ds] = *(const bfrag*)&Kb_[(l31 * 128 + ((ds * 32 + cA) ^ swz)) >> 1];
                k1[ds] = *(const bfrag*)&Kb_[((l31 + 32) * 128 + ((ds * 32 + cA) ^ swz)) >> 1];
            }
#pragma unroll
            for (int r = 0; r < 16; ++r) { Sn0[r] = 0.f; Sn1[r] = 0.f; }
            __builtin_amdgcn_s_setprio(1);
#pragma unroll
            for (int ds = 0; ds < 4; ++ds) Sn0 = mfma32(k0[ds], qB[ds], Sn0);
#pragma unroll
            for (int ds = 0; ds < 4; ++ds) Sn1 = mfma32(k1[ds], qB[ds], Sn1);
            __builtin_amdgcn_s_setprio(0);
        }

        // V fragments for PV(kt)
        const ushort* Vb_ = &KV[s0][4096];
        bfrag vF0[4], vF1[4];
#pragma unroll
        for (int c = 0; c < 4; ++c) {
            vF0[c] = *(const bfrag*)&Vb_[(l31 * 128 + ((c * 32 + cA) ^ swz)) >> 1];
            vF1[c] = *(const bfrag*)&Vb_[((l31 + 32) * 128 + ((c * 32 + cA) ^ swz)) >> 1];
        }

        // ... while softmax(kt) runs on the VALU pipe underneath
        float mx[8];
#pragma unroll
        for (int i = 0; i < 8; ++i)
            mx[i] = fmaxf(fmaxf(Sc0[i], Sc0[i + 8]), fmaxf(Sc1[i], Sc1[i + 8]));
        const float m4 = fmaxf(fmaxf(mx[0], mx[1]), fmaxf(mx[2], mx[3]));
        const float m5 = fmaxf(fmaxf(mx[4], mx[5]), fmaxf(mx[6], mx[7]));
        float pmax = fmaxf(m4, m5);
        pmax = fmaxf(pmax, __shfl_xor(pmax, 32));

        if (!__all(pmax - mrun <= 8.0f)) {   // defer-max (T13)
            const float mnew = fmaxf(mrun, pmax);
            const float rsc = __builtin_amdgcn_exp2f(mrun - mnew);
            mrun = mnew;
            lrun *= rsc;
#pragma unroll
            for (int r = 0; r < 16; ++r) { O0[r] *= rsc; O1[r] *= rsc; }
        }

        float p[32];
#pragma unroll
        for (int r = 0; r < 16; ++r) {
            p[r]      = __builtin_amdgcn_exp2f(Sc0[r] - mrun);
            p[16 + r] = __builtin_amdgcn_exp2f(Sc1[r] - mrun);
        }
        float s8[8];
#pragma unroll
        for (int i = 0; i < 8; ++i) s8[i] = (p[i] + p[i + 8]) + (p[i + 16] + p[i + 24]);
        float ssum = ((s8[0] + s8[1]) + (s8[2] + s8[3])) + ((s8[4] + s8[5]) + (s8[6] + s8[7]));
        ssum += __shfl_xor(ssum, 32);
        lrun += ssum;

        // pack P -> bf16 B-fragments, exchange-free (kv permuted by sigma; VPT matches)
        bfrag pB[4];
#pragma unroll
        for (int c = 0; c < 4; ++c) {
            union { v4u u; bfrag f; } cv;
#pragma unroll
            for (int wd = 0; wd < 4; ++wd)
                cv.u[wd] = pack_bf16x2(p[8 * c + 2 * wd], p[8 * c + 2 * wd + 1]);
            pB[c] = cv.f;
        }

        // PV (swapped): O^T += V^T-frag x P^T-frag
        __builtin_amdgcn_s_setprio(1);
#pragma unroll
        for (int c = 0; c < 4; ++c) O0 = mfma32(vF0[c], pB[c], O0);
#pragma unroll
        for (int c = 0; c < 4; ++c) O1 = mfma32(vF1[c], pB[c], O1);
        __builtin_amdgcn_s_setprio(0);
    };

    int s0 = 0, s1 = 1, s2 = 2;
#pragma unroll 1
    for (int t2 = 0; t2 < 16; ++t2) {
        STEP(SA0, SA1, SB0, SB1, 2 * t2, s0, s1, s2);
        { const int t = s0; s0 = s1; s1 = s2; s2 = t; }
        STEP(SB0, SB1, SA0, SA1, 2 * t2 + 1, s0, s1, s2);
        { const int t = s0; s0 = s1; s1 = s2; s2 = t; }
    }

    // epilogue: O^T / l -> AO[q][h*64+d], 8B packed stores
    const float inv = 1.f / lrun;
    ushort* Ao = AO + (size_t)(b * 2048 + qrow0 + l31) * 1024 + h * 64 + hi * 4;
#pragma unroll
    for (int t = 0; t < 2; ++t) {
#pragma unroll
        for (int g = 0; g < 4; ++g) {
            const float e0 = (t ? O1[4 * g + 0] : O0[4 * g + 0]) * inv;
            const float e1 = (t ? O1[4 * g + 1] : O0[4 * g + 1]) * inv;
            const float e2 = (t ? O1[4 * g + 2] : O0[4 * g + 2]) * inv;
            const float e3 = (t ? O1[4 * g + 3] : O0[4 * g + 3]) * inv;
            v2u pk = (v2u){pack_bf16x2(e0, e1), pack_bf16x2(e2, e3)};
            *(v2u*)(Ao + t * 32 + g * 8) = pk;
        }
    }
}

// ---------------- launcher ----------------

extern "C" void kernel_launch(void* const* d_in, const int* in_sizes, int n_in,
                              void* d_out, int out_size, void* d_ws, size_t ws_size,
                              hipStream_t stream) {
    (void)in_sizes; (void)n_in; (void)out_size; (void)ws_size;
    const float* q  = (const float*)d_in[0];
    const float* v  = (const float*)d_in[2];
    const float* Wq = (const float*)d_in[3];
    const float* bq = (const float*)d_in[4];
    const float* Wv = (const float*)d_in[7];
    const float* bv = (const float*)d_in[8];
    const float* Wo = (const float*)d_in[9];
    const float* bo = (const float*)d_in[10];
    float* out = (float*)d_out;
    char* ws = (char*)d_ws;
    const size_t MB = 1ull << 20;
    ushort* qbf = (ushort*)(ws + 0);         // 8MB (reused as AO)
    ushort* vbf = (ushort*)(ws + 8 * MB);    // 8MB
    ushort* WqT = (ushort*)(ws + 16 * MB);   // 2MB
    ushort* WvT = (ushort*)(ws + 18 * MB);   // 2MB
    ushort* WoT = (ushort*)(ws + 20 * MB);   // 2MB
    ushort* QPb = (ushort*)(ws + 22 * MB);   // 8MB
    ushort* VPb = (ushort*)(ws + 30 * MB);   // 8MB
    ushort* VPT = (ushort*)(ws + 38 * MB);   // 8MB
    ushort* AO  = qbf;                        // alias: qbf dead after q-proj GEMM

    cvt_bf16_2<<<8192, 256, 0, stream>>>(q, qbf, v, vbf, 1048576);
    cvt_T3<<<dim3(32, 32, 3), dim3(32, 8), 0, stream>>>(Wq, WqT, Wv, WvT, Wo, WoT);

    const float qscale = 0.125f * 1.44269504088896340736f;
    gemm_qv<<<dim3(8, 32, 2), 256, 0, stream>>>(qbf, WqT, bq, QPb,
                                                vbf, WvT, bv, VPb, VPT, qscale);
    attn_kernel<<<dim3(32, 16), 256, 0, stream>>>(QPb, VPb, VPT, AO);
    gemm_o<<<dim3(8, 32), 256, 0, stream>>>(AO, WoT, bo, out);
}